// Round 8
// baseline (31.467 us; speedup 1.0000x reference)
//
#include <hip/hip_runtime.h>

#define BATCH 4
#define NROWS 2048
#define IN_DIM 1024
#define OUT_DIM 512
#define DSPLIT 16
#define NCHUNK 256          // chunks total (64 per batch)
#define RPB 32              // rows per chunk

// ---- K1: w2part[ds][col] = sum_{d in slice} fc_w[d][col] * a2[d] ------
// 64 blocks (16 d-slices x 4 col-groups), 32 loads/thread.
__global__ void __launch_bounds__(256)
k1_w2part(const float* __restrict__ fc_w,
          const float* __restrict__ attn_w,
          float* __restrict__ w2part) {
    int ds = blockIdx.x >> 2, cg = blockIdx.x & 3;
    int col = (cg << 8) + threadIdx.x;
    int d0 = ds << 5;
    float acc = 0.f;
#pragma unroll 8
    for (int j = 0; j < 32; ++j)
        acc += fc_w[(size_t)(d0 + j) * IN_DIM + col] * attn_w[OUT_DIM + d0 + j];
    w2part[(ds << 10) + col] = acc;
}

// ---- K2: per-chunk flash pass: yu_c = sum_r e^{s2_r} x_r, Zc = sum e --
// 256 blocks x 512 threads; 8 waves x 4 rows; x read ONCE, held in regs.
__global__ void __launch_bounds__(512)
k2_chunk(const float* __restrict__ x,
         const float* __restrict__ w2part,
         float* __restrict__ yu,
         float* __restrict__ Zc) {
    const int bid = blockIdx.x, t = threadIdx.x;
    const int w = t >> 6, lane = t & 63;
    __shared__ float w2s[IN_DIM];                 // 4 KB
    __shared__ float4 sbuf[8 * 256];              // 32 KB
    __shared__ float zbuf[8];

    if (t < 256) {
        const float4* wp = (const float4*)w2part;
        float4 s = {0.f, 0.f, 0.f, 0.f};
#pragma unroll
        for (int ds = 0; ds < DSPLIT; ++ds) {
            float4 v = wp[(ds << 8) + t];
            s.x += v.x; s.y += v.y; s.z += v.z; s.w += v.w;
        }
        ((float4*)w2s)[t] = s;
    }
    __syncthreads();

    const float4* x4 = (const float4*)x;
    const float4* w2s4 = (const float4*)w2s;
    const float4 u0 = w2s4[lane],       u1 = w2s4[lane + 64],
                 u2 = w2s4[lane + 128], u3 = w2s4[lane + 192];

    size_t row0 = (size_t)bid * RPB + (w << 2);
    float4 a0 = {0,0,0,0}, a1 = {0,0,0,0}, a2 = {0,0,0,0}, a3 = {0,0,0,0};
    float zw = 0.f;
#pragma unroll
    for (int r = 0; r < 4; ++r) {
        size_t base = (row0 + r) << 8;
        float4 v0 = x4[base + lane];
        float4 v1 = x4[base + lane + 64];
        float4 v2 = x4[base + lane + 128];
        float4 v3 = x4[base + lane + 192];
        float d = v0.x*u0.x + v0.y*u0.y + v0.z*u0.z + v0.w*u0.w
                + v1.x*u1.x + v1.y*u1.y + v1.z*u1.z + v1.w*u1.w
                + v2.x*u2.x + v2.y*u2.y + v2.z*u2.z + v2.w*u2.w
                + v3.x*u3.x + v3.y*u3.y + v3.z*u3.z + v3.w*u3.w;
#pragma unroll
        for (int off = 32; off; off >>= 1) d += __shfl_xor(d, off, 64);
        float e = __expf(d);            // |s2| <~ 5: safe fp32; max-term cancels exactly
        zw += e;
        a0.x += e*v0.x; a0.y += e*v0.y; a0.z += e*v0.z; a0.w += e*v0.w;
        a1.x += e*v1.x; a1.y += e*v1.y; a1.z += e*v1.z; a1.w += e*v1.w;
        a2.x += e*v2.x; a2.y += e*v2.y; a2.z += e*v2.z; a2.w += e*v2.w;
        a3.x += e*v3.x; a3.y += e*v3.y; a3.z += e*v3.z; a3.w += e*v3.w;
    }
    sbuf[(w << 8) + lane]       = a0;
    sbuf[(w << 8) + lane + 64]  = a1;
    sbuf[(w << 8) + lane + 128] = a2;
    sbuf[(w << 8) + lane + 192] = a3;
    if (lane == 0) zbuf[w] = zw;
    __syncthreads();

    if (t < 256) {
        float4 s = {0.f, 0.f, 0.f, 0.f};
#pragma unroll
        for (int i = 0; i < 8; ++i) {
            float4 v = sbuf[(i << 8) + t];
            s.x += v.x; s.y += v.y; s.z += v.z; s.w += v.w;
        }
        ((float4*)(yu + ((size_t)bid << 10)))[t] = s;
        if (t == 0) {
            float z = 0.f;
#pragma unroll
            for (int i = 0; i < 8; ++i) z += zbuf[i];
            Zc[bid] = z;
        }
    }
}

// ---- K3: y merge (redundant) + c slice + out tile write ---------------
// 256 blocks: (b, ds in [0,16), rg in [0,4)). Each block:
//   merge full y for batch b, compute c[d] for d in [ds*32, ds*32+32),
//   write out rows [rg*512, rg*512+512) x cols [ds*32, ds*32+32)
//   -> per row 128 B contiguous, 128 B aligned (full cacheline).
__global__ void __launch_bounds__(256)
k3_fused(const float* __restrict__ yu,
         const float* __restrict__ Zc,
         const float* __restrict__ fc_w,
         const float* __restrict__ fc_b,
         float4* __restrict__ out) {
    const int bid = blockIdx.x;
    const int b = bid >> 6, rem = bid & 63, ds = rem >> 2, rg = rem & 3;
    const int t = threadIdx.x, w = t >> 6, lane = t & 63;
    __shared__ float ys[IN_DIM];
    __shared__ float cs[32];
    __shared__ float zsh;

    if (w == 0) {
        float z = Zc[(b << 6) + lane];
#pragma unroll
        for (int off = 32; off; off >>= 1) z += __shfl_xor(z, off, 64);
        if (lane == 0) zsh = 1.f / z;
    }

    // merge this batch's 64 chunk partials: thread t owns float4 col t
    const float4* yu4 = (const float4*)yu + ((size_t)b << 14);
    float4 acc = {0.f, 0.f, 0.f, 0.f};
#pragma unroll 8
    for (int c = 0; c < 64; ++c) {
        float4 v = yu4[(c << 8) + t];
        acc.x += v.x; acc.y += v.y; acc.z += v.z; acc.w += v.w;
    }
    __syncthreads();
    const float invZ = zsh;
    acc.x *= invZ; acc.y *= invZ; acc.z *= invZ; acc.w *= invZ;
    ((float4*)ys)[t] = acc;
    __syncthreads();

    // c-slice: wave w computes 8 d's
    const float4* ys4 = (const float4*)ys;
    const float4 y0 = ys4[lane],       y1 = ys4[lane + 64],
                 y2 = ys4[lane + 128], y3 = ys4[lane + 192];
#pragma unroll
    for (int q = 0; q < 8; ++q) {
        int dl = (w << 3) + q;
        int d = (ds << 5) + dl;
        const float4* fr = (const float4*)fc_w + ((size_t)d << 8);
        float4 f0 = fr[lane], f1 = fr[lane + 64], f2 = fr[lane + 128], f3 = fr[lane + 192];
        float s = f0.x*y0.x + f0.y*y0.y + f0.z*y0.z + f0.w*y0.w
                + f1.x*y1.x + f1.y*y1.y + f1.z*y1.z + f1.w*y1.w
                + f2.x*y2.x + f2.y*y2.y + f2.z*y2.z + f2.w*y2.w
                + f3.x*y3.x + f3.y*y3.y + f3.z*y3.z + f3.w*y3.w;
#pragma unroll
        for (int off = 32; off; off >>= 1) s += __shfl_xor(s, off, 64);
        if (lane == 0) cs[dl] = s + fc_b[d];
    }
    __syncthreads();

    // out tile write: thread t -> local row lr = t>>3, col4 = t&7
    const float4 val = ((const float4*)cs)[t & 7];
    const int lr = t >> 3;
    size_t rowbase = ((size_t)b * NROWS + (rg << 9) + lr) * 128 + (ds << 3) + (t & 7);
#pragma unroll
    for (int it = 0; it < 16; ++it)
        out[rowbase + (size_t)it * 32 * 128] = val;
}

extern "C" void kernel_launch(void* const* d_in, const int* in_sizes, int n_in,
                              void* d_out, int out_size, void* d_ws, size_t ws_size,
                              hipStream_t stream) {
    const float* x      = (const float*)d_in[0];
    const float* fc_w   = (const float*)d_in[1];
    const float* fc_b   = (const float*)d_in[2];
    const float* attn_w = (const float*)d_in[3];
    // attn_b (d_in[4]) cancels in the softmax — unused.

    float* wsf    = (float*)d_ws;
    float* w2part = wsf;                               // 16384
    float* Zc     = w2part + DSPLIT * IN_DIM;          // 256
    float* yu     = Zc + NCHUNK;                       // 262144
    float* out    = (float*)d_out;                     // total ws: 1.06 MB

    k1_w2part<<<64,     256, 0, stream>>>(fc_w, attn_w, w2part);
    k2_chunk <<<NCHUNK, 512, 0, stream>>>(x, w2part, yu, Zc);
    k3_fused <<<256,    256, 0, stream>>>(yu, Zc, fc_w, fc_b, (float4*)out);
}